// Round 14
// baseline (176.483 us; speedup 1.0000x reference)
//
#include <hip/hip_runtime.h>
#include <hip/hip_bf16.h>

#define F_IN 500
#define F_HID 16
#define F_OUT 3
#define BN 64            // fine bucket: dst-nodes per agg block
#define CBN 256          // coarse bucket: dst-nodes per partition slice
#define CAP 16384        // static edge capacity per coarse bucket (avg 8184, ~90 sigma)
#define CE 8192          // edges per chunk (partition build)
#define TILE 2048        // edges per sort-tile in agg kernels
#define MAXB 512         // static LDS bound, >= NCB=391
#define KCH 32           // gemm1 K-chunk (floats)
#define GROWS 128        // gemm1 rows per block (== threads per block)

__device__ __forceinline__ int clampi(int v, int lo, int hi) {
    return min(max(v, lo), hi);
}

__device__ __forceinline__ float bf2f(unsigned short u) {
    return __uint_as_float((unsigned)u << 16);
}

__device__ __forceinline__ unsigned short f2bf(float v) {
    __hip_bfloat16 h = __float2bfloat16(v);
    return *reinterpret_cast<unsigned short*>(&h);
}

// Single-pass coarse partition: per-chunk LDS hist -> global bulk-reserve -> scatter.
// Records (src<<8 | dst&255) land in static region [b*CAP, b*CAP + len_b).
__global__ __launch_bounds__(1024) void k_part(const int* __restrict__ ei, int E, int N,
                                               int NCB, int* __restrict__ cur,
                                               unsigned* __restrict__ ebufC) {
    __shared__ int lh[MAXB];
    __shared__ int loff[MAXB];
    __shared__ int lcnt[MAXB];
    int c = blockIdx.x;
    for (int i = threadIdx.x; i < NCB; i += 1024) lh[i] = 0;
    __syncthreads();
    int base = c * CE, lim = min(base + CE, E);
    for (int e = base + (int)threadIdx.x; e < lim; e += 1024) {
        int d = clampi(ei[(size_t)E + e], 0, N - 1);
        atomicAdd(&lh[d >> 8], 1);
    }
    __syncthreads();
    for (int i = threadIdx.x; i < NCB; i += 1024) {
        int cnt = lh[i];
        int rbase = cnt ? atomicAdd(&cur[i], cnt) : 0;
        loff[i] = i * CAP + rbase;
        lcnt[i] = 0;
    }
    __syncthreads();
    for (int e = base + (int)threadIdx.x; e < lim; e += 1024) {
        int s = clampi(ei[e], 0, N - 1);
        int d = clampi(ei[(size_t)E + e], 0, N - 1);
        int b = d >> 8;
        int pos = loff[b] + atomicAdd(&lcnt[b], 1);
        pos = min(pos, (b + 1) * CAP - 1);   // defensive: stay inside bucket region
        ebufC[pos] = ((unsigned)s << 8) | (unsigned)(d & 255);
    }
}

// C: per-coarse-bucket sub-partition into 4 fine buckets (contiguous within region),
// fused per-node degree -> dinv and fbstart/fend emission. No global atomics.
__global__ __launch_bounds__(1024) void k_passC(const unsigned* __restrict__ ebufC,
                                                const int* __restrict__ cur,
                                                unsigned* __restrict__ ebuf2,
                                                int* __restrict__ fbstart,
                                                int* __restrict__ fend,
                                                float* __restrict__ dinv, int N) {
    __shared__ int pcnt[CBN];
    __shared__ int soff[4], scur[4], scnt[4];
    int b = blockIdx.x, t = threadIdx.x;
    int cs = b * CAP;
    int blen = min(cur[b], CAP);
    int ce = cs + blen;
    if (t < CBN) pcnt[t] = 0;
    __syncthreads();
    for (int i = cs + t; i < ce; i += 1024) atomicAdd(&pcnt[ebufC[i] & 255], 1);
    __syncthreads();
    if (t == 0) {
        int r = 0;
#pragma unroll
        for (int s = 0; s < 4; ++s) {
            int c = 0;
            for (int j = s * 64; j < s * 64 + 64; ++j) c += pcnt[j];
            soff[s] = r;
            scur[s] = r;
            scnt[s] = c;
            r += c;
        }
    }
    __syncthreads();
    if (t < 4) {
        fbstart[b * 4 + t] = cs + soff[t];
        fend[b * 4 + t] = cs + soff[t] + scnt[t];
    }
    int node = b * CBN + t;
    if (t < CBN && node < N) dinv[node] = rsqrtf((float)pcnt[t] + 1.0f);
    __syncthreads();
    int lane = t & 63;
    unsigned long long ltm = (1ull << lane) - 1ull;
    for (int base = cs; base < ce; base += 1024) {
        int i = base + t;
        bool valid = i < ce;
        unsigned rec = valid ? ebufC[i] : 0u;
        int sub = (rec >> 6) & 3;
        unsigned frec = ((rec >> 8) << 6) | (rec & 63);
        int pos = 0;
        bool have = false;
#pragma unroll
        for (int s = 0; s < 4; ++s) {
            bool mine = valid && (sub == s);
            unsigned long long m = __ballot(mine);
            if (m) {
                int leader = __ffsll((unsigned long long)m) - 1;
                int cnt = __popcll(m);
                int bp = 0;
                if (lane == leader) bp = atomicAdd(&scur[s], cnt);
                bp = __shfl(bp, leader);
                if (mine) {
                    pos = bp + __popcll(m & ltm);
                    have = true;
                }
            }
        }
        if (have) ebuf2[cs + pos] = frec;
    }
}

// hs1b = bf16( (x @ W1) * dinv[row] )
// GEMV: lane == row (16 f32 accs), W via wave-uniform scalar loads,
// x staged global->reg->LDS with XOR-swizzled float4 slots.
__global__ __launch_bounds__(GROWS) void k_gemm1(const float* __restrict__ x,
                                                 const float* __restrict__ W1,
                                                 const float* __restrict__ dinv,
                                                 __hip_bfloat16* __restrict__ hs1b, int N) {
    __shared__ float xt[GROWS * KCH];
    const int t = threadIdx.x;
    const int row0 = blockIdx.x * GROWS;
    const int sw = t & 7;

    float acc[F_HID];
#pragma unroll
    for (int j = 0; j < F_HID; ++j) acc[j] = 0.f;

    float4 pf[8];

#define LOADC(c)                                                          \
    {                                                                     \
        _Pragma("unroll")                                                 \
        for (int i = 0; i < 8; ++i) {                                     \
            int f = i * GROWS + t;                                        \
            int r = f >> 3, c4 = f & 7;                                   \
            int gr = row0 + r, gk = (c) * KCH + c4 * 4;                   \
            float4 v = make_float4(0.f, 0.f, 0.f, 0.f);                   \
            if (gr < N && gk < F_IN)                                      \
                v = *(const float4*)(x + (size_t)gr * F_IN + gk);         \
            pf[i] = v;                                                    \
        }                                                                 \
    }

#define STOREC()                                                          \
    {                                                                     \
        _Pragma("unroll")                                                 \
        for (int i = 0; i < 8; ++i) {                                     \
            int f = i * GROWS + t;                                        \
            int r = f >> 3, c4 = f & 7;                                   \
            int slot = c4 ^ (r & 7);                                      \
            *(float4*)(xt + r * KCH + slot * 4) = pf[i];                  \
        }                                                                 \
    }

    LOADC(0);

    for (int c = 0; c < 16; ++c) {
        if (c > 0) __syncthreads();
        STOREC();
        __syncthreads();
        if (c < 15) LOADC(c + 1);

        float4 xld[8];
#pragma unroll
        for (int c4 = 0; c4 < 8; ++c4)
            xld[c4] = *(const float4*)(xt + t * KCH + ((c4 ^ sw) << 2));

        const float* wp = W1 + (size_t)c * KCH * F_HID;
        if (c < 15) {
#pragma unroll
            for (int c4 = 0; c4 < 8; ++c4) {
                float4 xv = xld[c4];
                const float* wr = wp + c4 * 64;
#pragma unroll
                for (int j = 0; j < 16; ++j) acc[j] = fmaf(xv.x, wr[j], acc[j]);
#pragma unroll
                for (int j = 0; j < 16; ++j) acc[j] = fmaf(xv.y, wr[16 + j], acc[j]);
#pragma unroll
                for (int j = 0; j < 16; ++j) acc[j] = fmaf(xv.z, wr[32 + j], acc[j]);
#pragma unroll
                for (int j = 0; j < 16; ++j) acc[j] = fmaf(xv.w, wr[48 + j], acc[j]);
            }
        } else {
            // tail chunk 15: k = 480..499 -> c4 = 0..4 (500 = 480 + 20)
#pragma unroll
            for (int c4 = 0; c4 < 5; ++c4) {
                float4 xv = xld[c4];
                const float* wr = wp + c4 * 64;
#pragma unroll
                for (int j = 0; j < 16; ++j) acc[j] = fmaf(xv.x, wr[j], acc[j]);
#pragma unroll
                for (int j = 0; j < 16; ++j) acc[j] = fmaf(xv.y, wr[16 + j], acc[j]);
#pragma unroll
                for (int j = 0; j < 16; ++j) acc[j] = fmaf(xv.z, wr[32 + j], acc[j]);
#pragma unroll
                for (int j = 0; j < 16; ++j) acc[j] = fmaf(xv.w, wr[48 + j], acc[j]);
            }
        }
    }
#undef LOADC
#undef STOREC

    int row = row0 + t;
    if (row < N) {
        float di = dinv[row];
        uint4 u0, u1;
        u0.x = ((unsigned)f2bf(acc[1] * di) << 16) | f2bf(acc[0] * di);
        u0.y = ((unsigned)f2bf(acc[3] * di) << 16) | f2bf(acc[2] * di);
        u0.z = ((unsigned)f2bf(acc[5] * di) << 16) | f2bf(acc[4] * di);
        u0.w = ((unsigned)f2bf(acc[7] * di) << 16) | f2bf(acc[6] * di);
        u1.x = ((unsigned)f2bf(acc[9] * di) << 16) | f2bf(acc[8] * di);
        u1.y = ((unsigned)f2bf(acc[11] * di) << 16) | f2bf(acc[10] * di);
        u1.z = ((unsigned)f2bf(acc[13] * di) << 16) | f2bf(acc[12] * di);
        u1.w = ((unsigned)f2bf(acc[15] * di) << 16) | f2bf(acc[14] * di);
        uint4* dst = (uint4*)((unsigned short*)hs1b + (size_t)row * F_HID);
        dst[0] = u0;
        dst[1] = u1;
    }
}

// agg layer1: tile counting-sort in LDS (int atomics only) + register accumulation
__global__ __launch_bounds__(256) void k_agg1g2(const unsigned* __restrict__ ebuf2,
                                                const int* __restrict__ fbstart,
                                                const int* __restrict__ fend,
                                                const __hip_bfloat16* __restrict__ hs1b,
                                                const float* __restrict__ b1,
                                                const float* __restrict__ W2,
                                                const float* __restrict__ dinv,
                                                float* __restrict__ hs2p, int N) {
    __shared__ unsigned rec[TILE];
    __shared__ unsigned srt[TILE];
    __shared__ int cnt[BN], offs[BN], ocur[BN];
    __shared__ float w2s[F_HID * F_OUT];
    __shared__ float b1s[F_HID];
    int b = blockIdx.x, t = threadIdx.x;
    if (t < F_HID * F_OUT) w2s[t] = W2[t];
    if (t < F_HID) b1s[t] = b1[t];
    int s0 = fbstart[b], s1 = fend[b];
    int nl = t >> 2, q = t & 3;
    float ac0 = 0.f, ac1 = 0.f, ac2 = 0.f, ac3 = 0.f;

    for (int tb = s0; tb < s1; tb += TILE) {
        int nv = min(TILE, s1 - tb);
        if (t < BN) cnt[t] = 0;
        for (int i = t; i < nv; i += 256) rec[i] = ebuf2[tb + i];
        __syncthreads();
        for (int i = t; i < nv; i += 256) atomicAdd(&cnt[rec[i] & 63], 1);
        __syncthreads();
        if (t < 64) {
            int v = cnt[t];
            int xp = v;
#pragma unroll
            for (int d = 1; d < 64; d <<= 1) {
                int y = __shfl_up(xp, d);
                if (t >= d) xp += y;
            }
            offs[t] = xp - v;
            ocur[t] = xp - v;
        }
        __syncthreads();
        for (int i = t; i < nv; i += 256) {
            unsigned r = rec[i];
            int pos = atomicAdd(&ocur[r & 63], 1);
            srt[pos] = r >> 6;
        }
        __syncthreads();
        int gs = offs[nl], ge = gs + cnt[nl];
        int i = gs;
        for (; i + 1 < ge; i += 2) {
            unsigned sA = srt[i], sB = srt[i + 1];
            ushort4 uA = *(const ushort4*)(hs1b + (size_t)sA * F_HID + q * 4);
            ushort4 uB = *(const ushort4*)(hs1b + (size_t)sB * F_HID + q * 4);
            ac0 += bf2f(uA.x) + bf2f(uB.x);
            ac1 += bf2f(uA.y) + bf2f(uB.y);
            ac2 += bf2f(uA.z) + bf2f(uB.z);
            ac3 += bf2f(uA.w) + bf2f(uB.w);
        }
        if (i < ge) {
            unsigned sA = srt[i];
            ushort4 uA = *(const ushort4*)(hs1b + (size_t)sA * F_HID + q * 4);
            ac0 += bf2f(uA.x);
            ac1 += bf2f(uA.y);
            ac2 += bf2f(uA.z);
            ac3 += bf2f(uA.w);
        }
        __syncthreads();
    }

    int node = b * BN + nl;
    if (node < N) {
        float di = dinv[node];
        const __hip_bfloat16* hp = hs1b + (size_t)node * F_HID + q * 4;
        ushort4 us = *(const ushort4*)hp;
        float v0 = fmaxf(b1s[q * 4 + 0] + di * (bf2f(us.x) + ac0), 0.f);
        float v1 = fmaxf(b1s[q * 4 + 1] + di * (bf2f(us.y) + ac1), 0.f);
        float v2 = fmaxf(b1s[q * 4 + 2] + di * (bf2f(us.z) + ac2), 0.f);
        float v3 = fmaxf(b1s[q * 4 + 3] + di * (bf2f(us.w) + ac3), 0.f);
        float o0 = v0 * w2s[(q * 4 + 0) * 3 + 0] + v1 * w2s[(q * 4 + 1) * 3 + 0] +
                   v2 * w2s[(q * 4 + 2) * 3 + 0] + v3 * w2s[(q * 4 + 3) * 3 + 0];
        float o1 = v0 * w2s[(q * 4 + 0) * 3 + 1] + v1 * w2s[(q * 4 + 1) * 3 + 1] +
                   v2 * w2s[(q * 4 + 2) * 3 + 1] + v3 * w2s[(q * 4 + 3) * 3 + 1];
        float o2 = v0 * w2s[(q * 4 + 0) * 3 + 2] + v1 * w2s[(q * 4 + 1) * 3 + 2] +
                   v2 * w2s[(q * 4 + 2) * 3 + 2] + v3 * w2s[(q * 4 + 3) * 3 + 2];
        o0 += __shfl_xor(o0, 1); o0 += __shfl_xor(o0, 2);
        o1 += __shfl_xor(o1, 1); o1 += __shfl_xor(o1, 2);
        o2 += __shfl_xor(o2, 1); o2 += __shfl_xor(o2, 2);
        if (q == 0) {
            float4 r = make_float4(o0 * di, o1 * di, o2 * di, 0.f);
            *(float4*)(hs2p + (size_t)node * 4) = r;
        }
    }
}

// agg layer2: same tile-sort, register accumulation + fused log_softmax
__global__ __launch_bounds__(256) void k_agg2lsm(const unsigned* __restrict__ ebuf2,
                                                 const int* __restrict__ fbstart,
                                                 const int* __restrict__ fend,
                                                 const float* __restrict__ hs2p,
                                                 const float* __restrict__ b2,
                                                 const float* __restrict__ dinv,
                                                 float* __restrict__ out, int N) {
    __shared__ unsigned rec[TILE];
    __shared__ unsigned srt[TILE];
    __shared__ int cnt[BN], offs[BN], ocur[BN];
    int b = blockIdx.x, t = threadIdx.x;
    int s0 = fbstart[b], s1 = fend[b];
    int nl = t >> 2, c = t & 3;
    float acc = 0.f;

    for (int tb = s0; tb < s1; tb += TILE) {
        int nv = min(TILE, s1 - tb);
        if (t < BN) cnt[t] = 0;
        for (int i = t; i < nv; i += 256) rec[i] = ebuf2[tb + i];
        __syncthreads();
        for (int i = t; i < nv; i += 256) atomicAdd(&cnt[rec[i] & 63], 1);
        __syncthreads();
        if (t < 64) {
            int v = cnt[t];
            int xp = v;
#pragma unroll
            for (int d = 1; d < 64; d <<= 1) {
                int y = __shfl_up(xp, d);
                if (t >= d) xp += y;
            }
            offs[t] = xp - v;
            ocur[t] = xp - v;
        }
        __syncthreads();
        for (int i = t; i < nv; i += 256) {
            unsigned r = rec[i];
            int pos = atomicAdd(&ocur[r & 63], 1);
            srt[pos] = r >> 6;
        }
        __syncthreads();
        int gs = offs[nl], ge = gs + cnt[nl];
        int i = gs;
        for (; i + 1 < ge; i += 2) {
            unsigned sA = srt[i], sB = srt[i + 1];
            acc += hs2p[(size_t)sA * 4 + c] + hs2p[(size_t)sB * 4 + c];
        }
        if (i < ge) acc += hs2p[(size_t)srt[i] * 4 + c];
        __syncthreads();
    }

    int node = b * BN + nl;
    if (node < N) {
        float di = dinv[node];
        float self = hs2p[(size_t)node * 4 + c];
        float bc = (c < 3) ? b2[c] : 0.f;
        float a = bc + di * (self + acc);
        int wbase = (t & 63) & ~3;
        float a0 = __shfl(a, wbase + 0);
        float a1 = __shfl(a, wbase + 1);
        float a2 = __shfl(a, wbase + 2);
        if (c < 3) {
            float m = fmaxf(a0, fmaxf(a1, a2));
            float l = logf(expf(a0 - m) + expf(a1 - m) + expf(a2 - m));
            out[(size_t)node * 3 + c] = a - m - l;
        }
    }
}

extern "C" void kernel_launch(void* const* d_in, const int* in_sizes, int n_in,
                              void* d_out, int out_size, void* d_ws, size_t ws_size,
                              hipStream_t stream) {
    const float* x = (const float*)d_in[0];
    const int* ei = (const int*)d_in[1];
    const float* W1 = (const float*)d_in[2];
    const float* b1 = (const float*)d_in[3];
    const float* W2 = (const float*)d_in[4];
    const float* b2 = (const float*)d_in[5];
    float* out = (float*)d_out;

    const int N = in_sizes[0] / F_IN;        // 100000
    const int E = in_sizes[1] / 2;           // 3200000
    const int NCB = (N + CBN - 1) / CBN;     // 391 coarse buckets (<=MAXB)
    const int NFB = (N + BN - 1) / BN;       // 1563 fine buckets (agg grid)
    const int NCH = (E + CE - 1) / CE;       // 391 chunks

    char* p = (char*)d_ws;
    auto alloc = [&](size_t bytes) {
        char* r = p;
        p += (bytes + 255) & ~(size_t)255;
        return r;
    };
    int*            cur     = (int*)alloc((size_t)NCB * 4);
    float*          dinv    = (float*)alloc((size_t)N * 4);
    int*            fbstart = (int*)alloc((size_t)NCB * 4 * 4);
    int*            fend    = (int*)alloc((size_t)NCB * 4 * 4);
    unsigned*       ebufC   = (unsigned*)alloc((size_t)NCB * CAP * 4);  // 25.6 MB
    unsigned*       ebuf2   = (unsigned*)alloc((size_t)NCB * CAP * 4);  // 25.6 MB
    __hip_bfloat16* hs1b    = (__hip_bfloat16*)alloc((size_t)N * F_HID * 2);
    float*          hs2p    = (float*)alloc((size_t)N * 4 * 4);

    hipMemsetAsync(cur, 0, (size_t)NCB * 4, stream);

    k_part<<<NCH, 1024, 0, stream>>>(ei, E, N, NCB, cur, ebufC);
    k_passC<<<NCB, 1024, 0, stream>>>(ebufC, cur, ebuf2, fbstart, fend, dinv, N);
    k_gemm1<<<(N + GROWS - 1) / GROWS, GROWS, 0, stream>>>(x, W1, dinv, hs1b, N);
    k_agg1g2<<<NFB, 256, 0, stream>>>(ebuf2, fbstart, fend, hs1b, b1, W2, dinv, hs2p, N);
    k_agg2lsm<<<NFB, 256, 0, stream>>>(ebuf2, fbstart, fend, hs2p, b2, dinv, out, N);
}

// Round 15
// 162.277 us; speedup vs baseline: 1.0875x; 1.0875x over previous
//
#include <hip/hip_runtime.h>
#include <hip/hip_bf16.h>

#define F_IN 500
#define F_HID 16
#define F_OUT 3
#define BN 64            // fine bucket: dst-nodes per agg block
#define CBN 256          // coarse bucket: dst-nodes per partition slice
#define CE 8192          // edges per chunk (partition build)
#define TILE 2048        // edges per sort-tile in agg kernels
#define MAXB 512         // static LDS bound, >= NCB=391
#define KCH 32           // gemm1 K-chunk (floats)
#define GROWS 128        // gemm1 rows per block (== threads per block)

__device__ __forceinline__ int clampi(int v, int lo, int hi) {
    return min(max(v, lo), hi);
}

__device__ __forceinline__ float bf2f(unsigned short u) {
    return __uint_as_float((unsigned)u << 16);
}

__device__ __forceinline__ unsigned short f2bf(float v) {
    __hip_bfloat16 h = __float2bfloat16(v);
    return *reinterpret_cast<unsigned short*>(&h);
}

// A: per-chunk coarse-bucket histogram (LDS int atomics only; NO global atomics)
__global__ __launch_bounds__(1024) void k_passA(const int* __restrict__ ei, int E, int N,
                                                int NCB, int* __restrict__ hist) {
    __shared__ int lh[MAXB];
    int c = blockIdx.x;
    for (int i = threadIdx.x; i < NCB; i += 1024) lh[i] = 0;
    __syncthreads();
    int base = c * CE, lim = min(base + CE, E);
    for (int e = base + (int)threadIdx.x; e < lim; e += 1024) {
        int d = clampi(ei[(size_t)E + e], 0, N - 1);
        atomicAdd(&lh[d >> 8], 1);
    }
    __syncthreads();
    for (int i = threadIdx.x; i < NCB; i += 1024) hist[(size_t)c * NCB + i] = lh[i];
}

// S1: exclusive scan down each coarse-bucket column (NCH<=512); tot[b]=column total
__global__ __launch_bounds__(512) void k_scanchunks(int* __restrict__ hist, int NCH,
                                                    int NCB, int* __restrict__ tot) {
    __shared__ int s[512];
    int b = blockIdx.x, t = threadIdx.x;
    int v = (t < NCH) ? hist[(size_t)t * NCB + b] : 0;
    s[t] = v;
    __syncthreads();
    for (int off = 1; off < 512; off <<= 1) {
        int add = (t >= off) ? s[t - off] : 0;
        __syncthreads();
        s[t] += add;
        __syncthreads();
    }
    if (t < NCH) hist[(size_t)t * NCB + b] = s[t] - v;
    if (t == 511) tot[b] = s[511];
}

// S2: exclusive scan over NCB coarse totals (NCB<=512) -> cbstart
__global__ __launch_bounds__(512) void k_scanbuckets(const int* __restrict__ tot, int NCB,
                                                     int E, int* __restrict__ cbstart) {
    __shared__ int s[512];
    int t = threadIdx.x;
    int v = (t < NCB) ? tot[t] : 0;
    s[t] = v;
    __syncthreads();
    for (int off = 1; off < 512; off <<= 1) {
        int add = (t >= off) ? s[t - off] : 0;
        __syncthreads();
        s[t] += add;
        __syncthreads();
    }
    if (t < NCB) cbstart[t] = s[t] - v;
    if (t == 0) cbstart[NCB] = E;
}

// B: scatter coarse records (src<<8 | dst&255) into coarse-bucket-grouped ebufC
__global__ __launch_bounds__(1024) void k_passB(const int* __restrict__ ei, int E, int N,
                                                int NCB, const int* __restrict__ hist,
                                                const int* __restrict__ cbstart,
                                                unsigned* __restrict__ ebufC) {
    __shared__ int loff[MAXB];
    __shared__ int lcnt[MAXB];
    int c = blockIdx.x;
    for (int i = threadIdx.x; i < NCB; i += 1024) {
        loff[i] = cbstart[i] + hist[(size_t)c * NCB + i];
        lcnt[i] = 0;
    }
    __syncthreads();
    int base = c * CE, lim = min(base + CE, E);
    for (int e = base + (int)threadIdx.x; e < lim; e += 1024) {
        int s = clampi(ei[e], 0, N - 1);
        int d = clampi(ei[(size_t)E + e], 0, N - 1);
        int b = d >> 8;
        int pos = loff[b] + atomicAdd(&lcnt[b], 1);
        ebufC[pos] = ((unsigned)s << 8) | (unsigned)(d & 255);
    }
}

// C: per-coarse-bucket sub-partition into 4 fine buckets (contiguous writes),
// fused per-node degree -> dinv and fbstart emission. No global atomics.
__global__ __launch_bounds__(1024) void k_passC(const unsigned* __restrict__ ebufC,
                                                const int* __restrict__ cbstart,
                                                unsigned* __restrict__ ebuf2,
                                                int* __restrict__ fbstart,
                                                float* __restrict__ dinv, int N) {
    __shared__ int pcnt[CBN];
    __shared__ int soff[4], scur[4];
    int b = blockIdx.x, t = threadIdx.x;
    int cs = cbstart[b], ce = cbstart[b + 1];
    if (t < CBN) pcnt[t] = 0;
    __syncthreads();
    for (int i = cs + t; i < ce; i += 1024) atomicAdd(&pcnt[ebufC[i] & 255], 1);
    __syncthreads();
    if (t == 0) {
        int r = 0;
#pragma unroll
        for (int s = 0; s < 4; ++s) {
            int c = 0;
            for (int j = s * 64; j < s * 64 + 64; ++j) c += pcnt[j];
            soff[s] = r;
            scur[s] = r;
            r += c;
        }
    }
    __syncthreads();
    if (t < 4) fbstart[b * 4 + t] = cs + soff[t];
    int node = b * CBN + t;
    if (t < CBN && node < N) dinv[node] = rsqrtf((float)pcnt[t] + 1.0f);
    __syncthreads();
    int lane = t & 63;
    unsigned long long ltm = (1ull << lane) - 1ull;
    for (int base = cs; base < ce; base += 1024) {
        int i = base + t;
        bool valid = i < ce;
        unsigned rec = valid ? ebufC[i] : 0u;
        int sub = (rec >> 6) & 3;
        unsigned frec = ((rec >> 8) << 6) | (rec & 63);
        int pos = 0;
        bool have = false;
#pragma unroll
        for (int s = 0; s < 4; ++s) {
            bool mine = valid && (sub == s);
            unsigned long long m = __ballot(mine);
            if (m) {
                int leader = __ffsll((unsigned long long)m) - 1;
                int cnt = __popcll(m);
                int bp = 0;
                if (lane == leader) bp = atomicAdd(&scur[s], cnt);
                bp = __shfl(bp, leader);
                if (mine) {
                    pos = bp + __popcll(m & ltm);
                    have = true;
                }
            }
        }
        if (have) ebuf2[cs + pos] = frec;
    }
}

// hs1b = bf16( (x @ W1) * dinv[row] )
// GEMV: lane == row (16 f32 accs), W via wave-uniform scalar loads,
// x staged global->reg->LDS with XOR-swizzled float4 slots.
__global__ __launch_bounds__(GROWS) void k_gemm1(const float* __restrict__ x,
                                                 const float* __restrict__ W1,
                                                 const float* __restrict__ dinv,
                                                 __hip_bfloat16* __restrict__ hs1b, int N) {
    __shared__ float xt[GROWS * KCH];
    const int t = threadIdx.x;
    const int row0 = blockIdx.x * GROWS;
    const int sw = t & 7;

    float acc[F_HID];
#pragma unroll
    for (int j = 0; j < F_HID; ++j) acc[j] = 0.f;

    float4 pf[8];

#define LOADC(c)                                                          \
    {                                                                     \
        _Pragma("unroll")                                                 \
        for (int i = 0; i < 8; ++i) {                                     \
            int f = i * GROWS + t;                                        \
            int r = f >> 3, c4 = f & 7;                                   \
            int gr = row0 + r, gk = (c) * KCH + c4 * 4;                   \
            float4 v = make_float4(0.f, 0.f, 0.f, 0.f);                   \
            if (gr < N && gk < F_IN)                                      \
                v = *(const float4*)(x + (size_t)gr * F_IN + gk);         \
            pf[i] = v;                                                    \
        }                                                                 \
    }

#define STOREC()                                                          \
    {                                                                     \
        _Pragma("unroll")                                                 \
        for (int i = 0; i < 8; ++i) {                                     \
            int f = i * GROWS + t;                                        \
            int r = f >> 3, c4 = f & 7;                                   \
            int slot = c4 ^ (r & 7);                                      \
            *(float4*)(xt + r * KCH + slot * 4) = pf[i];                  \
        }                                                                 \
    }

    LOADC(0);

    for (int c = 0; c < 16; ++c) {
        if (c > 0) __syncthreads();
        STOREC();
        __syncthreads();
        if (c < 15) LOADC(c + 1);

        float4 xld[8];
#pragma unroll
        for (int c4 = 0; c4 < 8; ++c4)
            xld[c4] = *(const float4*)(xt + t * KCH + ((c4 ^ sw) << 2));

        const float* wp = W1 + (size_t)c * KCH * F_HID;
        if (c < 15) {
#pragma unroll
            for (int c4 = 0; c4 < 8; ++c4) {
                float4 xv = xld[c4];
                const float* wr = wp + c4 * 64;
#pragma unroll
                for (int j = 0; j < 16; ++j) acc[j] = fmaf(xv.x, wr[j], acc[j]);
#pragma unroll
                for (int j = 0; j < 16; ++j) acc[j] = fmaf(xv.y, wr[16 + j], acc[j]);
#pragma unroll
                for (int j = 0; j < 16; ++j) acc[j] = fmaf(xv.z, wr[32 + j], acc[j]);
#pragma unroll
                for (int j = 0; j < 16; ++j) acc[j] = fmaf(xv.w, wr[48 + j], acc[j]);
            }
        } else {
            // tail chunk 15: k = 480..499 -> c4 = 0..4 (500 = 480 + 20)
#pragma unroll
            for (int c4 = 0; c4 < 5; ++c4) {
                float4 xv = xld[c4];
                const float* wr = wp + c4 * 64;
#pragma unroll
                for (int j = 0; j < 16; ++j) acc[j] = fmaf(xv.x, wr[j], acc[j]);
#pragma unroll
                for (int j = 0; j < 16; ++j) acc[j] = fmaf(xv.y, wr[16 + j], acc[j]);
#pragma unroll
                for (int j = 0; j < 16; ++j) acc[j] = fmaf(xv.z, wr[32 + j], acc[j]);
#pragma unroll
                for (int j = 0; j < 16; ++j) acc[j] = fmaf(xv.w, wr[48 + j], acc[j]);
            }
        }
    }
#undef LOADC
#undef STOREC

    int row = row0 + t;
    if (row < N) {
        float di = dinv[row];
        uint4 u0, u1;
        u0.x = ((unsigned)f2bf(acc[1] * di) << 16) | f2bf(acc[0] * di);
        u0.y = ((unsigned)f2bf(acc[3] * di) << 16) | f2bf(acc[2] * di);
        u0.z = ((unsigned)f2bf(acc[5] * di) << 16) | f2bf(acc[4] * di);
        u0.w = ((unsigned)f2bf(acc[7] * di) << 16) | f2bf(acc[6] * di);
        u1.x = ((unsigned)f2bf(acc[9] * di) << 16) | f2bf(acc[8] * di);
        u1.y = ((unsigned)f2bf(acc[11] * di) << 16) | f2bf(acc[10] * di);
        u1.z = ((unsigned)f2bf(acc[13] * di) << 16) | f2bf(acc[12] * di);
        u1.w = ((unsigned)f2bf(acc[15] * di) << 16) | f2bf(acc[14] * di);
        uint4* dst = (uint4*)((unsigned short*)hs1b + (size_t)row * F_HID);
        dst[0] = u0;
        dst[1] = u1;
    }
}

// agg layer1: tile counting-sort in LDS (int atomics only) + register accumulation
__global__ __launch_bounds__(256) void k_agg1g2(const unsigned* __restrict__ ebuf2,
                                                const int* __restrict__ bstart,
                                                const __hip_bfloat16* __restrict__ hs1b,
                                                const float* __restrict__ b1,
                                                const float* __restrict__ W2,
                                                const float* __restrict__ dinv,
                                                float* __restrict__ hs2p, int N) {
    __shared__ unsigned rec[TILE];
    __shared__ unsigned srt[TILE];
    __shared__ int cnt[BN], offs[BN], ocur[BN];
    __shared__ float w2s[F_HID * F_OUT];
    __shared__ float b1s[F_HID];
    int b = blockIdx.x, t = threadIdx.x;
    if (t < F_HID * F_OUT) w2s[t] = W2[t];
    if (t < F_HID) b1s[t] = b1[t];
    int s0 = bstart[b], s1 = bstart[b + 1];
    int nl = t >> 2, q = t & 3;
    float ac0 = 0.f, ac1 = 0.f, ac2 = 0.f, ac3 = 0.f;

    for (int tb = s0; tb < s1; tb += TILE) {
        int nv = min(TILE, s1 - tb);
        if (t < BN) cnt[t] = 0;
        for (int i = t; i < nv; i += 256) rec[i] = ebuf2[tb + i];
        __syncthreads();
        for (int i = t; i < nv; i += 256) atomicAdd(&cnt[rec[i] & 63], 1);
        __syncthreads();
        if (t < 64) {
            int v = cnt[t];
            int xp = v;
#pragma unroll
            for (int d = 1; d < 64; d <<= 1) {
                int y = __shfl_up(xp, d);
                if (t >= d) xp += y;
            }
            offs[t] = xp - v;
            ocur[t] = xp - v;
        }
        __syncthreads();
        for (int i = t; i < nv; i += 256) {
            unsigned r = rec[i];
            int pos = atomicAdd(&ocur[r & 63], 1);
            srt[pos] = r >> 6;
        }
        __syncthreads();
        int gs = offs[nl], ge = gs + cnt[nl];
        int i = gs;
        for (; i + 1 < ge; i += 2) {
            unsigned sA = srt[i], sB = srt[i + 1];
            ushort4 uA = *(const ushort4*)(hs1b + (size_t)sA * F_HID + q * 4);
            ushort4 uB = *(const ushort4*)(hs1b + (size_t)sB * F_HID + q * 4);
            ac0 += bf2f(uA.x) + bf2f(uB.x);
            ac1 += bf2f(uA.y) + bf2f(uB.y);
            ac2 += bf2f(uA.z) + bf2f(uB.z);
            ac3 += bf2f(uA.w) + bf2f(uB.w);
        }
        if (i < ge) {
            unsigned sA = srt[i];
            ushort4 uA = *(const ushort4*)(hs1b + (size_t)sA * F_HID + q * 4);
            ac0 += bf2f(uA.x);
            ac1 += bf2f(uA.y);
            ac2 += bf2f(uA.z);
            ac3 += bf2f(uA.w);
        }
        __syncthreads();
    }

    int node = b * BN + nl;
    if (node < N) {
        float di = dinv[node];
        const __hip_bfloat16* hp = hs1b + (size_t)node * F_HID + q * 4;
        ushort4 us = *(const ushort4*)hp;
        float v0 = fmaxf(b1s[q * 4 + 0] + di * (bf2f(us.x) + ac0), 0.f);
        float v1 = fmaxf(b1s[q * 4 + 1] + di * (bf2f(us.y) + ac1), 0.f);
        float v2 = fmaxf(b1s[q * 4 + 2] + di * (bf2f(us.z) + ac2), 0.f);
        float v3 = fmaxf(b1s[q * 4 + 3] + di * (bf2f(us.w) + ac3), 0.f);
        float o0 = v0 * w2s[(q * 4 + 0) * 3 + 0] + v1 * w2s[(q * 4 + 1) * 3 + 0] +
                   v2 * w2s[(q * 4 + 2) * 3 + 0] + v3 * w2s[(q * 4 + 3) * 3 + 0];
        float o1 = v0 * w2s[(q * 4 + 0) * 3 + 1] + v1 * w2s[(q * 4 + 1) * 3 + 1] +
                   v2 * w2s[(q * 4 + 2) * 3 + 1] + v3 * w2s[(q * 4 + 3) * 3 + 1];
        float o2 = v0 * w2s[(q * 4 + 0) * 3 + 2] + v1 * w2s[(q * 4 + 1) * 3 + 2] +
                   v2 * w2s[(q * 4 + 2) * 3 + 2] + v3 * w2s[(q * 4 + 3) * 3 + 2];
        o0 += __shfl_xor(o0, 1); o0 += __shfl_xor(o0, 2);
        o1 += __shfl_xor(o1, 1); o1 += __shfl_xor(o1, 2);
        o2 += __shfl_xor(o2, 1); o2 += __shfl_xor(o2, 2);
        if (q == 0) {
            float4 r = make_float4(o0 * di, o1 * di, o2 * di, 0.f);
            *(float4*)(hs2p + (size_t)node * 4) = r;
        }
    }
}

// agg layer2: same tile-sort, register accumulation + fused log_softmax
__global__ __launch_bounds__(256) void k_agg2lsm(const unsigned* __restrict__ ebuf2,
                                                 const int* __restrict__ bstart,
                                                 const float* __restrict__ hs2p,
                                                 const float* __restrict__ b2,
                                                 const float* __restrict__ dinv,
                                                 float* __restrict__ out, int N) {
    __shared__ unsigned rec[TILE];
    __shared__ unsigned srt[TILE];
    __shared__ int cnt[BN], offs[BN], ocur[BN];
    int b = blockIdx.x, t = threadIdx.x;
    int s0 = bstart[b], s1 = bstart[b + 1];
    int nl = t >> 2, c = t & 3;
    float acc = 0.f;

    for (int tb = s0; tb < s1; tb += TILE) {
        int nv = min(TILE, s1 - tb);
        if (t < BN) cnt[t] = 0;
        for (int i = t; i < nv; i += 256) rec[i] = ebuf2[tb + i];
        __syncthreads();
        for (int i = t; i < nv; i += 256) atomicAdd(&cnt[rec[i] & 63], 1);
        __syncthreads();
        if (t < 64) {
            int v = cnt[t];
            int xp = v;
#pragma unroll
            for (int d = 1; d < 64; d <<= 1) {
                int y = __shfl_up(xp, d);
                if (t >= d) xp += y;
            }
            offs[t] = xp - v;
            ocur[t] = xp - v;
        }
        __syncthreads();
        for (int i = t; i < nv; i += 256) {
            unsigned r = rec[i];
            int pos = atomicAdd(&ocur[r & 63], 1);
            srt[pos] = r >> 6;
        }
        __syncthreads();
        int gs = offs[nl], ge = gs + cnt[nl];
        int i = gs;
        for (; i + 1 < ge; i += 2) {
            unsigned sA = srt[i], sB = srt[i + 1];
            acc += hs2p[(size_t)sA * 4 + c] + hs2p[(size_t)sB * 4 + c];
        }
        if (i < ge) acc += hs2p[(size_t)srt[i] * 4 + c];
        __syncthreads();
    }

    int node = b * BN + nl;
    if (node < N) {
        float di = dinv[node];
        float self = hs2p[(size_t)node * 4 + c];
        float bc = (c < 3) ? b2[c] : 0.f;
        float a = bc + di * (self + acc);
        int wbase = (t & 63) & ~3;
        float a0 = __shfl(a, wbase + 0);
        float a1 = __shfl(a, wbase + 1);
        float a2 = __shfl(a, wbase + 2);
        if (c < 3) {
            float m = fmaxf(a0, fmaxf(a1, a2));
            float l = logf(expf(a0 - m) + expf(a1 - m) + expf(a2 - m));
            out[(size_t)node * 3 + c] = a - m - l;
        }
    }
}

extern "C" void kernel_launch(void* const* d_in, const int* in_sizes, int n_in,
                              void* d_out, int out_size, void* d_ws, size_t ws_size,
                              hipStream_t stream) {
    const float* x = (const float*)d_in[0];
    const int* ei = (const int*)d_in[1];
    const float* W1 = (const float*)d_in[2];
    const float* b1 = (const float*)d_in[3];
    const float* W2 = (const float*)d_in[4];
    const float* b2 = (const float*)d_in[5];
    float* out = (float*)d_out;

    const int N = in_sizes[0] / F_IN;        // 100000
    const int E = in_sizes[1] / 2;           // 3200000
    const int NCB = (N + CBN - 1) / CBN;     // 391 coarse buckets
    const int NFB = (N + BN - 1) / BN;       // 1563 fine buckets (agg grid)
    const int NCH = (E + CE - 1) / CE;       // 391 chunks

    char* p = (char*)d_ws;
    auto alloc = [&](size_t bytes) {
        char* r = p;
        p += (bytes + 255) & ~(size_t)255;
        return r;
    };
    float*          dinv    = (float*)alloc((size_t)N * 4);
    int*            hist    = (int*)alloc((size_t)NCH * NCB * 4);
    int*            tot     = (int*)alloc((size_t)NCB * 4);
    int*            cbstart = (int*)alloc(((size_t)NCB + 1) * 4);
    int*            fbstart = (int*)alloc(((size_t)NCB * 4 + 1) * 4);
    unsigned*       ebufC   = (unsigned*)alloc((size_t)E * 4);
    unsigned*       ebuf2   = (unsigned*)alloc((size_t)E * 4);
    __hip_bfloat16* hs1b    = (__hip_bfloat16*)alloc((size_t)N * F_HID * 2);
    float*          hs2p    = (float*)alloc((size_t)N * 4 * 4);

    k_passA<<<NCH, 1024, 0, stream>>>(ei, E, N, NCB, hist);
    k_scanchunks<<<NCB, 512, 0, stream>>>(hist, NCH, NCB, tot);
    k_scanbuckets<<<1, 512, 0, stream>>>(tot, NCB, E, cbstart);
    k_passB<<<NCH, 1024, 0, stream>>>(ei, E, N, NCB, hist, cbstart, ebufC);
    k_passC<<<NCB, 1024, 0, stream>>>(ebufC, cbstart, ebuf2, fbstart, dinv, N);
    k_gemm1<<<(N + GROWS - 1) / GROWS, GROWS, 0, stream>>>(x, W1, dinv, hs1b, N);
    k_agg1g2<<<NFB, 256, 0, stream>>>(ebuf2, fbstart, hs1b, b1, W2, dinv, hs2p, N);
    k_agg2lsm<<<NFB, 256, 0, stream>>>(ebuf2, fbstart, hs2p, b2, dinv, out, N);
}